// Round 2
// baseline (2076.845 us; speedup 1.0000x reference)
//
#include <hip/hip_runtime.h>

typedef __bf16 bf16;
typedef __bf16 bf16x4 __attribute__((ext_vector_type(4)));
typedef __bf16 bf16x8 __attribute__((ext_vector_type(8)));
typedef float  f32x4  __attribute__((ext_vector_type(4)));

#define PMAX 12
#define DEMB 512
#define BM 128
#define BN 128
#define BK 32

// ---------------- prep: W [R][C] f32 -> WT [C][R] bf16 (R,C multiples of 32) ----------------
__global__ __launch_bounds__(256)
void transpose_to_bf16(const float* __restrict__ W, bf16* __restrict__ WT, int R, int C)
{
    __shared__ float tile[32][33];
    const int bx = blockIdx.x * 32;   // C base
    const int by = blockIdx.y * 32;   // R base
    const int tx = threadIdx.x & 31, ty = threadIdx.x >> 5;  // 32 x 8
#pragma unroll
    for (int i = 0; i < 32; i += 8)
        tile[ty + i][tx] = W[(size_t)(by + ty + i) * C + bx + tx];
    __syncthreads();
#pragma unroll
    for (int i = 0; i < 32; i += 8)
        WT[(size_t)(bx + ty + i) * R + by + tx] = (bf16)tile[tx][ty + i];
}

__global__ __launch_bounds__(256)
void concat_bias_kernel(const float* __restrict__ a, const float* __restrict__ b,
                        float* __restrict__ o)
{
    int i = blockIdx.x * 256 + threadIdx.x;
    o[i] = (i < 512) ? a[i] : b[i - 512];
}

// ---------------- generic GEMM:  C[M x Nout] = [A1(f32,K1) | A2(bf16,K2)] @ BT^T + bias ----
// BT: [Nout][K1+K2] bf16 (pre-transposed weight).  Output to Cf (f32) or Cb (bf16).
__global__ __launch_bounds__(256)
void gemm_kernel(const float* __restrict__ A1, const bf16* __restrict__ A2,
                 const int K1, const int K2,
                 const bf16* __restrict__ BT, const float* __restrict__ bias,
                 const int M, float* __restrict__ Cf, bf16* __restrict__ Cb,
                 const int ldc)
{
    __shared__ bf16 As[BM][BK + 8];   // +8 pad: row stride 80B -> 2-way bank alias only (free, m136)
    __shared__ bf16 Bs[BN][BK + 8];

    const int tid  = threadIdx.x;
    const int m0   = blockIdx.x * BM;
    const int n0   = blockIdx.y * BN;
    const int K    = K1 + K2;
    const int lane = tid & 63;
    const int wid  = tid >> 6;
    const int wr   = wid >> 1, wc = wid & 1;   // 2x2 waves, each 64x64 out
    const int lm   = lane & 15, qg = lane >> 4;

    f32x4 acc[4][4] = {};

    const int rs = tid >> 3;          // staging: 8 threads/row, 32 rows/pass
    const int kc = (tid & 7) * 4;     // 4 elements each

    for (int k0 = 0; k0 < K; k0 += BK) {
        if (k0 < K1) {  // f32 source (uniform branch; BK divides K1)
#pragma unroll
            for (int pass = 0; pass < 4; ++pass) {
                const int r  = rs + pass * 32;
                const int gm = m0 + r;
                float4 v = {0.f, 0.f, 0.f, 0.f};
                if (gm < M) v = *reinterpret_cast<const float4*>(&A1[(size_t)gm * K1 + k0 + kc]);
                bf16x4 h = { (bf16)v.x, (bf16)v.y, (bf16)v.z, (bf16)v.w };
                *reinterpret_cast<bf16x4*>(&As[r][kc]) = h;
            }
        } else {        // bf16 source
#pragma unroll
            for (int pass = 0; pass < 4; ++pass) {
                const int r  = rs + pass * 32;
                const int gm = m0 + r;
                bf16x4 h = {};
                if (gm < M) h = *reinterpret_cast<const bf16x4*>(&A2[(size_t)gm * K2 + (k0 - K1) + kc]);
                *reinterpret_cast<bf16x4*>(&As[r][kc]) = h;
            }
        }
#pragma unroll
        for (int pass = 0; pass < 4; ++pass) {
            const int r = rs + pass * 32;
            *reinterpret_cast<bf16x4*>(&Bs[r][kc]) =
                *reinterpret_cast<const bf16x4*>(&BT[(size_t)(n0 + r) * K + k0 + kc]);
        }
        __syncthreads();

        bf16x8 af[4], bfr[4];
#pragma unroll
        for (int i = 0; i < 4; ++i)
            af[i] = *reinterpret_cast<const bf16x8*>(&As[wr * 64 + i * 16 + lm][qg * 8]);
#pragma unroll
        for (int j = 0; j < 4; ++j)
            bfr[j] = *reinterpret_cast<const bf16x8*>(&Bs[wc * 64 + j * 16 + lm][qg * 8]);
#pragma unroll
        for (int i = 0; i < 4; ++i)
#pragma unroll
            for (int j = 0; j < 4; ++j)
                acc[i][j] = __builtin_amdgcn_mfma_f32_16x16x32_bf16(af[i], bfr[j], acc[i][j], 0, 0, 0);
        __syncthreads();
    }

    // epilogue: D col = lane&15, row = 4*(lane>>4)+reg  [HW-verified m89/m91]
#pragma unroll
    for (int i = 0; i < 4; ++i)
#pragma unroll
        for (int j = 0; j < 4; ++j) {
            const int col = n0 + wc * 64 + j * 16 + lm;
            const float bb = bias[col];
#pragma unroll
            for (int r = 0; r < 4; ++r) {
                const int row = m0 + wr * 64 + i * 16 + qg * 4 + r;
                if (row < M) {
                    const float v = acc[i][j][r] + bb;
                    if (Cf) Cf[(size_t)row * ldc + col] = v;
                    else    Cb[(size_t)row * ldc + col] = (bf16)v;
                }
            }
        }
}

// ---------------- attention: one wave per node ----------------
// Q: [nn][512] bf16 (chunk base); KV: [nn*12][1024] bf16 (cols 0-511 = K, 512-1023 = V)
__global__ __launch_bounds__(256)
void attn_kernel(const bf16* __restrict__ Q, const bf16* __restrict__ KV,
                 const int* __restrict__ lens, bf16* __restrict__ att, const int n_nodes)
{
    const int w    = threadIdx.x >> 6;
    const int lane = threadIdx.x & 63;
    const int n    = blockIdx.x * 4 + w;
    if (n >= n_nodes) return;
    const int L = lens[n];

    // lane covers output dims [lane*8, lane*8+8) -> head = lane>>3; 8-lane groups share a head
    float qv[8];
    {
        bf16x8 qb = *reinterpret_cast<const bf16x8*>(&Q[(size_t)n * DEMB + lane * 8]);
#pragma unroll
        for (int j = 0; j < 8; ++j) qv[j] = (float)qb[j];
    }

    const bf16* kvb = KV + (size_t)n * PMAX * 1024;
    float sc[PMAX];
#pragma unroll
    for (int p = 0; p < PMAX; ++p) {
        float s = -1e30f;
        if (p < L) {                     // wave-uniform branch
            bf16x8 kb = *reinterpret_cast<const bf16x8*>(&kvb[p * 1024 + lane * 8]);
            float t = 0.f;
#pragma unroll
            for (int j = 0; j < 8; ++j) t += qv[j] * (float)kb[j];
            t += __shfl_xor(t, 1);       // reduce d over the 8-lane head group
            t += __shfl_xor(t, 2);
            t += __shfl_xor(t, 4);
            s = t;
        }
        sc[p] = s;
    }
    // softmax over p<L (computed redundantly in every lane of the head group)
    float mx = sc[0];
#pragma unroll
    for (int p = 1; p < PMAX; ++p) mx = fmaxf(mx, sc[p]);
    float sum = 0.f;
#pragma unroll
    for (int p = 0; p < PMAX; ++p) { sc[p] = __expf(sc[p] - mx); sum += sc[p]; }  // masked -> 0
    const float inv = 1.f / sum;

    float acc[8] = {0.f,0.f,0.f,0.f,0.f,0.f,0.f,0.f};
#pragma unroll
    for (int p = 0; p < PMAX; ++p) {
        if (p >= L) break;               // wave-uniform
        const float wgt = sc[p] * inv;
        bf16x8 vb = *reinterpret_cast<const bf16x8*>(&kvb[p * 1024 + 512 + lane * 8]);
#pragma unroll
        for (int j = 0; j < 8; ++j) acc[j] += wgt * (float)vb[j];
    }
    bf16x8 o;
#pragma unroll
    for (int j = 0; j < 8; ++j) o[j] = (bf16)acc[j];
    *reinterpret_cast<bf16x8*>(&att[(size_t)n * DEMB + lane * 8]) = o;
}

// ---------------- launch ----------------
extern "C" void kernel_launch(void* const* d_in, const int* in_sizes, int n_in,
                              void* d_out, int out_size, void* d_ws, size_t ws_size,
                              hipStream_t stream)
{
    const float* x   = (const float*)d_in[0];
    const float* pe  = (const float*)d_in[1];
    const int*   len = (const int*)d_in[2];
    const float* Wq  = (const float*)d_in[3];
    const float* bq  = (const float*)d_in[4];
    const float* Wk  = (const float*)d_in[5];
    const float* bk  = (const float*)d_in[6];
    const float* Wv  = (const float*)d_in[7];
    const float* bv  = (const float*)d_in[8];
    const float* Wo  = (const float*)d_in[9];
    const float* bo  = (const float*)d_in[10];
    float* out = (float*)d_out;

    const int n  = in_sizes[0] / DEMB;   // 20000

    char* ws = (char*)d_ws;
    size_t off = 0;
    auto alloc = [&](size_t bytes) -> char* {
        char* p = ws + off;
        off += (bytes + 255) & ~(size_t)255;
        return p;
    };
    bf16*  WqT  = (bf16*)alloc((size_t)512 * 512 * 2);
    bf16*  WkvT = (bf16*)alloc((size_t)1024 * 512 * 2);   // rows 0-511 Wk^T, 512-1023 Wv^T
    bf16*  WoT  = (bf16*)alloc((size_t)512 * 1024 * 2);
    float* bkv  = (float*)alloc(1024 * 4);
    bf16*  Qb   = (bf16*)alloc((size_t)n * DEMB * 2);
    bf16*  attb = (bf16*)alloc((size_t)n * DEMB * 2);
    (void)n_in; (void)out_size;

    // KV chunk buffer: whatever workspace remains decides nodes-per-chunk.
    const size_t per_node = (size_t)PMAX * 1024 * 2;              // 24,576 B
    const size_t kv_avail = (ws_size > off) ? (ws_size - off) : 0;
    long long npc_ll = (long long)(kv_avail / per_node);
    int npc = (npc_ll >= n) ? n : (int)npc_ll;
    if (npc < 1) npc = 1;                                          // degenerate safety
    bf16* KVb = (bf16*)(ws + off);

    // prep
    transpose_to_bf16<<<dim3(16, 16), 256, 0, stream>>>(Wq, WqT, 512, 512);
    transpose_to_bf16<<<dim3(16, 16), 256, 0, stream>>>(Wk, WkvT, 512, 512);
    transpose_to_bf16<<<dim3(16, 16), 256, 0, stream>>>(Wv, WkvT + (size_t)512 * 512, 512, 512);
    transpose_to_bf16<<<dim3(16, 32), 256, 0, stream>>>(Wo, WoT, 1024, 512);
    concat_bias_kernel<<<4, 256, 0, stream>>>(bk, bv, bkv);

    // Q = x @ Wq + bq  -> bf16
    gemm_kernel<<<dim3((n + BM - 1) / BM, 512 / BN), 256, 0, stream>>>(
        x, nullptr, 512, 0, WqT, bq, n, nullptr, Qb, 512);

    // per chunk: KV = personas @ [Wk|Wv] + [bk|bv] -> bf16 [nn*12][1024]; then attention
    for (int node0 = 0; node0 < n; node0 += npc) {
        const int nn = (n - node0 < npc) ? (n - node0) : npc;
        const int M  = nn * PMAX;
        gemm_kernel<<<dim3((M + BM - 1) / BM, 1024 / BN), 256, 0, stream>>>(
            pe + (size_t)node0 * PMAX * 512, nullptr, 512, 0, WkvT, bkv, M, nullptr, KVb, 1024);
        attn_kernel<<<dim3((nn + 3) / 4), 256, 0, stream>>>(
            Qb + (size_t)node0 * DEMB, KVb, len + node0, attb + (size_t)node0 * DEMB, nn);
    }

    // out = [x || att] @ Wo + bo -> f32
    gemm_kernel<<<dim3((n + BM - 1) / BM, 512 / BN), 256, 0, stream>>>(
        x, attb, 512, 512, WoT, bo, n, out, nullptr, 512);
}

// Round 4
// 1539.589 us; speedup vs baseline: 1.3490x; 1.3490x over previous
//
#include <hip/hip_runtime.h>
#include <stdint.h>

typedef __bf16 bf16;
typedef __bf16 bf16x4 __attribute__((ext_vector_type(4)));
typedef __bf16 bf16x8 __attribute__((ext_vector_type(8)));
typedef float  f32x4  __attribute__((ext_vector_type(4)));

#define PMAX 12
#define DEMB 512

// async global->LDS, 16B per lane; LDS dest = wave-uniform base + lane*16 (m97/m104)
__device__ __forceinline__ void gload_lds16(const void* g, void* l) {
    __builtin_amdgcn_global_load_lds(
        (const __attribute__((address_space(1))) unsigned int*)g,
        (__attribute__((address_space(3))) unsigned int*)l, 16, 0, 0);
}

// ---------------- prep kernels ----------------
__global__ __launch_bounds__(256)
void transpose_to_bf16(const float* __restrict__ W, bf16* __restrict__ WT, int R, int C)
{
    __shared__ float tile[32][33];
    const int bx = blockIdx.x * 32;   // C base
    const int by = blockIdx.y * 32;   // R base
    const int tx = threadIdx.x & 31, ty = threadIdx.x >> 5;
#pragma unroll
    for (int i = 0; i < 32; i += 8)
        tile[ty + i][tx] = W[(size_t)(by + ty + i) * C + bx + tx];
    __syncthreads();
#pragma unroll
    for (int i = 0; i < 32; i += 8)
        WT[(size_t)(bx + ty + i) * R + by + tx] = (bf16)tile[tx][ty + i];
}

__global__ __launch_bounds__(256)
void concat_bias_kernel(const float* __restrict__ a, const float* __restrict__ b,
                        float* __restrict__ o)
{
    int i = blockIdx.x * 256 + threadIdx.x;
    o[i] = (i < 512) ? a[i] : b[i - 512];
}

// x [n][512] f32 -> xa [n][1024] bf16 (cols 0-511; cols 512+ filled by attention)
__global__ __launch_bounds__(256)
void x_to_xa(const float* __restrict__ x, bf16* __restrict__ xa, int total8)
{
    int i = blockIdx.x * 256 + threadIdx.x;
    if (i >= total8) return;
    int row = i >> 6, g = i & 63;
    const float4 v0 = *reinterpret_cast<const float4*>(&x[(size_t)row * 512 + g * 8]);
    const float4 v1 = *reinterpret_cast<const float4*>(&x[(size_t)row * 512 + g * 8 + 4]);
    bf16x8 h = {(bf16)v0.x,(bf16)v0.y,(bf16)v0.z,(bf16)v0.w,
                (bf16)v1.x,(bf16)v1.y,(bf16)v1.z,(bf16)v1.w};
    *reinterpret_cast<bf16x8*>(&xa[(size_t)row * 1024 + g * 8]) = h;
}

// ---------------- m97-class GEMM ----------------
// C[M x N] = A @ BT^T + bias.  BT: [N][K] bf16 (pre-transposed weight), K % 64 == 0.
// A: bf16 [M][lda] (gload_lds path) or f32 [M][lda] (reg-staged convert path, AF32).
// grid: x = N/128 (fast-varying -> blocks sharing an A panel are dispatch-adjacent),
//       y = ceil(M/128).
template<bool AF32>
__global__ __launch_bounds__(256)
void gemm97(const void* __restrict__ Av, const int lda,
            const bf16* __restrict__ BT, const float* __restrict__ bias,
            const int M, const int K,
            float* __restrict__ Cf, bf16* __restrict__ Cb, const int ldc)
{
    __shared__ bf16 As[128 * 64];   // linear [row][64] — required by global_load_lds
    __shared__ bf16 Bs[128 * 64];

    const int tid  = threadIdx.x;
    const int lane = tid & 63, wid = tid >> 6;
    const int wr   = wid >> 1,  wc  = wid & 1;       // 2x2 waves, 64x64 out each
    const int lm   = lane & 15, qg  = lane >> 4;
    const int n0   = blockIdx.x * 128;
    const int m0   = blockIdx.y * 128;

    const int srow = wid * 8 + (lane >> 3);          // gload: row within 32-row call
    const int scol = (lane & 7) * 8;                 // gload: col (bf16 elems)
    const int fcol = (tid & 15) * 4;                 // f32 path: col (f32 elems)

    f32x4 acc[4][4] = {};

    for (int k0 = 0; k0 < K; k0 += 64) {
        // stage B [128][64] via global_load_lds (rows n0.. always valid: N % 128 == 0)
#pragma unroll
        for (int c = 0; c < 4; ++c)
            gload_lds16(&BT[(size_t)(n0 + c * 32 + srow) * K + k0 + scol],
                        &Bs[c * 2048 + wid * 512]);
        // stage A [128][64]
        if (AF32) {
            const float* A = (const float*)Av;
#pragma unroll
            for (int p = 0; p < 8; ++p) {
                const int r  = p * 16 + (tid >> 4);
                const int gr = (m0 + r < M) ? (m0 + r) : (M - 1);
                float4 v = *reinterpret_cast<const float4*>(&A[(size_t)gr * lda + k0 + fcol]);
                bf16x4 h = {(bf16)v.x, (bf16)v.y, (bf16)v.z, (bf16)v.w};
                *reinterpret_cast<bf16x4*>(&As[r * 64 + fcol]) = h;
            }
        } else {
            const bf16* A = (const bf16*)Av;
#pragma unroll
            for (int c = 0; c < 4; ++c) {
                const int r  = c * 32 + srow;
                const int gr = (m0 + r < M) ? (m0 + r) : (M - 1);
                gload_lds16(&A[(size_t)gr * lda + k0 + scol],
                            &As[c * 2048 + wid * 512]);
            }
        }
        __syncthreads();   // drains vmcnt+lgkmcnt (compiler-guaranteed)

#pragma unroll
        for (int kh = 0; kh < 2; ++kh) {
            bf16x8 af[4], bfr[4];
#pragma unroll
            for (int i = 0; i < 4; ++i)
                af[i] = *reinterpret_cast<const bf16x8*>(
                    &As[(wr * 64 + i * 16 + lm) * 64 + kh * 32 + qg * 8]);
#pragma unroll
            for (int j = 0; j < 4; ++j)
                bfr[j] = *reinterpret_cast<const bf16x8*>(
                    &Bs[(wc * 64 + j * 16 + lm) * 64 + kh * 32 + qg * 8]);
#pragma unroll
            for (int i = 0; i < 4; ++i)
#pragma unroll
                for (int j = 0; j < 4; ++j)
                    acc[i][j] = __builtin_amdgcn_mfma_f32_16x16x32_bf16(
                        af[i], bfr[j], acc[i][j], 0, 0, 0);
        }
        __syncthreads();
    }

    // epilogue: D col = lane&15, row = 4*(lane>>4)+reg  [HW-verified m89/m91]
#pragma unroll
    for (int i = 0; i < 4; ++i)
#pragma unroll
        for (int j = 0; j < 4; ++j) {
            const int col = n0 + wc * 64 + j * 16 + lm;
            const float bb = bias[col];
#pragma unroll
            for (int r = 0; r < 4; ++r) {
                const int row = m0 + wr * 64 + i * 16 + qg * 4 + r;
                if (row < M) {
                    const float v = acc[i][j][r] + bb;
                    if (Cf) Cf[(size_t)row * ldc + col] = v;
                    else    Cb[(size_t)row * ldc + col] = (bf16)v;
                }
            }
        }
}

// ---------------- attention: one wave per node ----------------
// Q: [nn][512] bf16; KV: [nn*12][1024] bf16 (cols 0-511 K, 512-1023 V);
// att: output base (already col-offset), row stride ldatt.
__global__ __launch_bounds__(256)
void attn_kernel(const bf16* __restrict__ Q, const bf16* __restrict__ KV,
                 const int* __restrict__ lens, bf16* __restrict__ att,
                 const int ldatt, const int n_nodes)
{
    const int w    = threadIdx.x >> 6;
    const int lane = threadIdx.x & 63;
    const int n    = blockIdx.x * 4 + w;
    if (n >= n_nodes) return;
    const int L = lens[n];

    float qv[8];
    {
        bf16x8 qb = *reinterpret_cast<const bf16x8*>(&Q[(size_t)n * DEMB + lane * 8]);
#pragma unroll
        for (int j = 0; j < 8; ++j) qv[j] = (float)qb[j];
    }

    const bf16* kvb = KV + (size_t)n * PMAX * 1024;
    float sc[PMAX];
#pragma unroll
    for (int p = 0; p < PMAX; ++p) {
        float s = -1e30f;
        if (p < L) {                     // wave-uniform
            bf16x8 kb = *reinterpret_cast<const bf16x8*>(&kvb[p * 1024 + lane * 8]);
            float t = 0.f;
#pragma unroll
            for (int j = 0; j < 8; ++j) t += qv[j] * (float)kb[j];
            t += __shfl_xor(t, 1);
            t += __shfl_xor(t, 2);
            t += __shfl_xor(t, 4);
            s = t;
        }
        sc[p] = s;
    }
    float mx = sc[0];
#pragma unroll
    for (int p = 1; p < PMAX; ++p) mx = fmaxf(mx, sc[p]);
    float sum = 0.f;
#pragma unroll
    for (int p = 0; p < PMAX; ++p) { sc[p] = __expf(sc[p] - mx); sum += sc[p]; }
    const float inv = 1.f / sum;

    float acc[8] = {};
#pragma unroll
    for (int p = 0; p < PMAX; ++p) {
        if (p >= L) break;               // wave-uniform
        const float wgt = sc[p] * inv;
        bf16x8 vb = *reinterpret_cast<const bf16x8*>(&kvb[p * 1024 + 512 + lane * 8]);
#pragma unroll
        for (int j = 0; j < 8; ++j) acc[j] += wgt * (float)vb[j];
    }
    bf16x8 o;
#pragma unroll
    for (int j = 0; j < 8; ++j) o[j] = (bf16)acc[j];
    *reinterpret_cast<bf16x8*>(&att[(size_t)n * ldatt + lane * 8]) = o;
}

// ---------------- launch ----------------
extern "C" void kernel_launch(void* const* d_in, const int* in_sizes, int n_in,
                              void* d_out, int out_size, void* d_ws, size_t ws_size,
                              hipStream_t stream)
{
    const float* x   = (const float*)d_in[0];
    const float* pe  = (const float*)d_in[1];
    const int*   len = (const int*)d_in[2];
    const float* Wq  = (const float*)d_in[3];
    const float* bq  = (const float*)d_in[4];
    const float* Wk  = (const float*)d_in[5];
    const float* bk  = (const float*)d_in[6];
    const float* Wv  = (const float*)d_in[7];
    const float* bv  = (const float*)d_in[8];
    const float* Wo  = (const float*)d_in[9];
    const float* bo  = (const float*)d_in[10];
    float* out = (float*)d_out;

    const int n = in_sizes[0] / DEMB;    // 20000

    char* ws = (char*)d_ws;
    size_t off = 0;
    auto alloc = [&](size_t bytes) -> char* {
        char* p = ws + off;
        off += (bytes + 255) & ~(size_t)255;
        return p;
    };
    bf16*  WqT  = (bf16*)alloc((size_t)512 * 512 * 2);
    bf16*  WkvT = (bf16*)alloc((size_t)1024 * 512 * 2);  // rows 0-511 Wk^T, 512-1023 Wv^T
    bf16*  WoT  = (bf16*)alloc((size_t)512 * 1024 * 2);
    float* bkv  = (float*)alloc(1024 * 4);
    bf16*  Qb   = (bf16*)alloc((size_t)n * 512 * 2);
    bf16*  xa   = (bf16*)alloc((size_t)n * 1024 * 2);    // [x_bf16 || att]
    (void)n_in; (void)out_size;

    // KV chunk buffer sized from remaining workspace (graph-safe: constants only)
    const size_t per_node = (size_t)PMAX * 1024 * 2;
    const size_t kv_avail = (ws_size > off) ? (ws_size - off) : 0;
    long long npc_ll = (long long)(kv_avail / per_node);
    int npc = (npc_ll >= n) ? n : (int)npc_ll;
    if (npc < 1) npc = 1;
    bf16* KVb = (bf16*)(ws + off);

    // prep
    transpose_to_bf16<<<dim3(16, 16), 256, 0, stream>>>(Wq, WqT, 512, 512);
    transpose_to_bf16<<<dim3(16, 16), 256, 0, stream>>>(Wk, WkvT, 512, 512);
    transpose_to_bf16<<<dim3(16, 16), 256, 0, stream>>>(Wv, WkvT + (size_t)512 * 512, 512, 512);
    transpose_to_bf16<<<dim3(16, 32), 256, 0, stream>>>(Wo, WoT, 1024, 512);
    concat_bias_kernel<<<4, 256, 0, stream>>>(bk, bv, bkv);
    x_to_xa<<<(n * 64 + 255) / 256, 256, 0, stream>>>(x, xa, n * 64);

    // Q = x @ Wq + bq -> Qb bf16 [n][512]
    gemm97<false><<<dim3(512 / 128, (n + 127) / 128), 256, 0, stream>>>(
        xa, 1024, WqT, bq, n, 512, nullptr, Qb, 512);

    // per chunk: KV = personas @ [Wk|Wv] + [bk|bv] -> KVb bf16 [nn*12][1024]; then attn
    for (int node0 = 0; node0 < n; node0 += npc) {
        const int nn = (n - node0 < npc) ? (n - node0) : npc;
        const int M  = nn * PMAX;
        gemm97<true><<<dim3(1024 / 128, (M + 127) / 128), 256, 0, stream>>>(
            pe + (size_t)node0 * PMAX * 512, 512, WkvT, bkv, M, 512, nullptr, KVb, 1024);
        attn_kernel<<<dim3((nn + 3) / 4), 256, 0, stream>>>(
            Qb + (size_t)node0 * 512, KVb, len + node0,
            xa + (size_t)node0 * 1024 + 512, 1024, nn);
    }

    // out = [x || att] @ Wo + bo -> f32 [n][512]
    gemm97<false><<<dim3(512 / 128, (n + 127) / 128), 256, 0, stream>>>(
        xa, 1024, WoT, bo, n, 1024, out, nullptr, 512);
}

// Round 9
// 1138.787 us; speedup vs baseline: 1.8237x; 1.3520x over previous
//
#include <hip/hip_runtime.h>
#include <stdint.h>

typedef __bf16 bf16;
typedef __bf16 bf16x4 __attribute__((ext_vector_type(4)));
typedef __bf16 bf16x8 __attribute__((ext_vector_type(8)));
typedef float  f32x4  __attribute__((ext_vector_type(4)));

#define PMAX 12
#define DEMB 512

// async global->LDS, 16B per lane; LDS dest = wave-uniform base + lane*16 (m97/m104)
__device__ __forceinline__ void gload_lds16(const void* g, void* l) {
    __builtin_amdgcn_global_load_lds(
        (const __attribute__((address_space(1))) unsigned int*)g,
        (__attribute__((address_space(3))) unsigned int*)l, 16, 0, 0);
}

// ---------------- prep kernels ----------------
__global__ __launch_bounds__(256)
void transpose_to_bf16(const float* __restrict__ W, bf16* __restrict__ WT, int R, int C)
{
    __shared__ float tile[32][33];
    const int bx = blockIdx.x * 32;   // C base
    const int by = blockIdx.y * 32;   // R base
    const int tx = threadIdx.x & 31, ty = threadIdx.x >> 5;
#pragma unroll
    for (int i = 0; i < 32; i += 8)
        tile[ty + i][tx] = W[(size_t)(by + ty + i) * C + bx + tx];
    __syncthreads();
#pragma unroll
    for (int i = 0; i < 32; i += 8)
        WT[(size_t)(bx + ty + i) * R + by + tx] = (bf16)tile[tx][ty + i];
}

__global__ __launch_bounds__(256)
void concat_bias_kernel(const float* __restrict__ a, const float* __restrict__ b,
                        float* __restrict__ o)
{
    int i = blockIdx.x * 256 + threadIdx.x;
    o[i] = (i < 512) ? a[i] : b[i - 512];
}

// x [n][512] f32 -> xa [n][1024] bf16 (cols 0-511; cols 512+ filled by attention)
__global__ __launch_bounds__(256)
void x_to_xa(const float* __restrict__ x, bf16* __restrict__ xa, int total8)
{
    int i = blockIdx.x * 256 + threadIdx.x;
    if (i >= total8) return;
    int row = i >> 6, g = i & 63;
    const float4 v0 = *reinterpret_cast<const float4*>(&x[(size_t)row * 512 + g * 8]);
    const float4 v1 = *reinterpret_cast<const float4*>(&x[(size_t)row * 512 + g * 8 + 4]);
    bf16x8 h = {(bf16)v0.x,(bf16)v0.y,(bf16)v0.z,(bf16)v0.w,
                (bf16)v1.x,(bf16)v1.y,(bf16)v1.z,(bf16)v1.w};
    *reinterpret_cast<bf16x8*>(&xa[(size_t)row * 1024 + g * 8]) = h;
}

// exclusive prefix sum of lens -> start[]; total -> mlive[0]. Single block, 1024 thr.
__global__ __launch_bounds__(1024)
void scan_lens(const int* __restrict__ lens, const int n,
               int* __restrict__ start, int* __restrict__ mlive)
{
    __shared__ int buf[1024];
    __shared__ int carry;
    const int tid = threadIdx.x;
    if (tid == 0) carry = 0;
    __syncthreads();
    for (int c0 = 0; c0 < n; c0 += 1024) {
        const int i = c0 + tid;
        const int v = (i < n) ? lens[i] : 0;
        buf[tid] = v;
        __syncthreads();
        for (int ofs = 1; ofs < 1024; ofs <<= 1) {
            int t = (tid >= ofs) ? buf[tid - ofs] : 0;
            __syncthreads();
            buf[tid] += t;
            __syncthreads();
        }
        if (i < n) start[i] = carry + buf[tid] - v;
        __syncthreads();
        if (tid == 1023) carry += buf[1023];
        __syncthreads();
    }
    if (tid == 0) mlive[0] = carry;
}

// idxb[start[n]+j] = n*PMAX+j for j < lens[n]
__global__ __launch_bounds__(256)
void build_idx(const int* __restrict__ lens, const int* __restrict__ start,
               int* __restrict__ idxb, const int n)
{
    int node = blockIdx.x * 256 + threadIdx.x;
    if (node >= n) return;
    const int s = start[node], L = lens[node];
    for (int j = 0; j < L; ++j) idxb[s + j] = node * PMAX + j;
}

// ---------------- m97-class GEMM with XCD panel-grouping swizzle ----------------
// C[M x N] = A @ BT^T + bias.  BT: [N][K] bf16, K%64==0, N = NT*128 (NT = 1<<LNT).
// AMODE: 0 = bf16 A via global_load_lds; 1 = f32 A reg-convert; 2 = f32 A indexed rows.
// 1-D grid of MT_pad8*NT blocks. Block d: m_off=d&7 (== its XCD under d%8 round-robin),
// nt=(d>>3)&(NT-1), m_tile=(d>>(3+LNT))*8+m_off -> all NT panel-sharers of an m-tile
// run consecutively on ONE XCD => A-panel fetched ~once per panel.
template<int AMODE, int LNT>
__global__ __launch_bounds__(256)
void gemm97(const void* __restrict__ Av, const int lda,
            const bf16* __restrict__ BT, const float* __restrict__ bias,
            const int M, const int* __restrict__ Mlive_ptr,
            const int* __restrict__ idxb, const int K,
            float* __restrict__ Cf, bf16* __restrict__ Cb, const int ldc)
{
    const int d     = blockIdx.x;
    const int mt    = (d >> (3 + LNT)) * 8 + (d & 7);
    const int n0    = ((d >> 3) & ((1 << LNT) - 1)) * 128;
    const int Mlive = Mlive_ptr ? *Mlive_ptr : M;
    const int m0    = mt * 128;
    if (m0 >= Mlive) return;

    __shared__ bf16 As[128 * 64];   // linear — required by global_load_lds
    __shared__ bf16 Bs[128 * 64];

    const int tid  = threadIdx.x;
    const int lane = tid & 63, wid = tid >> 6;
    const int wr   = wid >> 1,  wc  = wid & 1;       // 2x2 waves, 64x64 out each
    const int lm   = lane & 15, qg  = lane >> 4;

    const int srow = wid * 8 + (lane >> 3);          // gload: row within 32-row call
    const int scol = (lane & 7) * 8;                 // gload: col (bf16 elems)
    const int fcol = (tid & 15) * 4;                 // f32 path: col (f32 elems)

    int gidx[8];
    if (AMODE == 2) {
#pragma unroll
        for (int p = 0; p < 8; ++p) {
            int m = m0 + p * 16 + (tid >> 4);
            gidx[p] = idxb[(m < Mlive) ? m : (Mlive - 1)];
        }
    }

    f32x4 acc[4][4] = {};

    for (int k0 = 0; k0 < K; k0 += 64) {
#pragma unroll
        for (int c = 0; c < 4; ++c)
            gload_lds16(&BT[(size_t)(n0 + c * 32 + srow) * K + k0 + scol],
                        &Bs[c * 2048 + wid * 512]);
        if (AMODE == 0) {
            const bf16* A = (const bf16*)Av;
#pragma unroll
            for (int c = 0; c < 4; ++c) {
                const int r  = c * 32 + srow;
                const int gr = (m0 + r < Mlive) ? (m0 + r) : (Mlive - 1);
                gload_lds16(&A[(size_t)gr * lda + k0 + scol],
                            &As[c * 2048 + wid * 512]);
            }
        } else {
            const float* A = (const float*)Av;
#pragma unroll
            for (int p = 0; p < 8; ++p) {
                const int r   = p * 16 + (tid >> 4);
                size_t arow;
                if (AMODE == 2) arow = (size_t)gidx[p];
                else {
                    const int gr = (m0 + r < Mlive) ? (m0 + r) : (Mlive - 1);
                    arow = (size_t)gr;
                }
                float4 v = *reinterpret_cast<const float4*>(&A[arow * lda + k0 + fcol]);
                bf16x4 h = {(bf16)v.x, (bf16)v.y, (bf16)v.z, (bf16)v.w};
                *reinterpret_cast<bf16x4*>(&As[r * 64 + fcol]) = h;
            }
        }
        __syncthreads();

#pragma unroll
        for (int kh = 0; kh < 2; ++kh) {
            bf16x8 af[4], bfr[4];
#pragma unroll
            for (int i = 0; i < 4; ++i)
                af[i] = *reinterpret_cast<const bf16x8*>(
                    &As[(wr * 64 + i * 16 + lm) * 64 + kh * 32 + qg * 8]);
#pragma unroll
            for (int j = 0; j < 4; ++j)
                bfr[j] = *reinterpret_cast<const bf16x8*>(
                    &Bs[(wc * 64 + j * 16 + lm) * 64 + kh * 32 + qg * 8]);
#pragma unroll
            for (int i = 0; i < 4; ++i)
#pragma unroll
                for (int j = 0; j < 4; ++j)
                    acc[i][j] = __builtin_amdgcn_mfma_f32_16x16x32_bf16(
                        af[i], bfr[j], acc[i][j], 0, 0, 0);
        }
        __syncthreads();
    }

    // epilogue: D col = lane&15, row = 4*(lane>>4)+reg  [HW-verified m89/m91]
#pragma unroll
    for (int i = 0; i < 4; ++i)
#pragma unroll
        for (int j = 0; j < 4; ++j) {
            const int col = n0 + wc * 64 + j * 16 + lm;
            const float bb = bias[col];
#pragma unroll
            for (int r = 0; r < 4; ++r) {
                const int row = m0 + wr * 64 + i * 16 + qg * 4 + r;
                if (row < Mlive) {
                    const float v = acc[i][j][r] + bb;
                    if (Cf) Cf[(size_t)row * ldc + col] = v;
                    else    Cb[(size_t)row * ldc + col] = (bf16)v;
                }
            }
        }
}

// ---------------- attention: one wave per node ----------------
// KV rows for node n start at (start?start[n]:n*PMAX); cols 0-511 K, 512-1023 V.
__global__ __launch_bounds__(256)
void attn_kernel(const bf16* __restrict__ Q, const bf16* __restrict__ KV,
                 const int* __restrict__ lens, const int* __restrict__ start,
                 bf16* __restrict__ att, const int ldatt, const int n_nodes)
{
    const int w    = threadIdx.x >> 6;
    const int lane = threadIdx.x & 63;
    const int n    = blockIdx.x * 4 + w;
    if (n >= n_nodes) return;
    const int L = lens[n];
    const size_t base = (size_t)(start ? start[n] : n * PMAX) * 1024;

    float qv[8];
    {
        bf16x8 qb = *reinterpret_cast<const bf16x8*>(&Q[(size_t)n * DEMB + lane * 8]);
#pragma unroll
        for (int j = 0; j < 8; ++j) qv[j] = (float)qb[j];
    }

    const bf16* kvb = KV + base;
    float sc[PMAX];
#pragma unroll
    for (int p = 0; p < PMAX; ++p) {
        float s = -1e30f;
        if (p < L) {                     // wave-uniform
            bf16x8 kb = *reinterpret_cast<const bf16x8*>(&kvb[p * 1024 + lane * 8]);
            float t = 0.f;
#pragma unroll
            for (int j = 0; j < 8; ++j) t += qv[j] * (float)kb[j];
            t += __shfl_xor(t, 1);
            t += __shfl_xor(t, 2);
            t += __shfl_xor(t, 4);
            s = t;
        }
        sc[p] = s;
    }
    float mx = sc[0];
#pragma unroll
    for (int p = 1; p < PMAX; ++p) mx = fmaxf(mx, sc[p]);
    float sum = 0.f;
#pragma unroll
    for (int p = 0; p < PMAX; ++p) { sc[p] = __expf(sc[p] - mx); sum += sc[p]; }
    const float inv = 1.f / sum;

    float acc[8] = {};
#pragma unroll
    for (int p = 0; p < PMAX; ++p) {
        if (p >= L) break;               // wave-uniform
        const float wgt = sc[p] * inv;
        bf16x8 vb = *reinterpret_cast<const bf16x8*>(&kvb[p * 1024 + 512 + lane * 8]);
#pragma unroll
        for (int j = 0; j < 8; ++j) acc[j] += wgt * (float)vb[j];
    }
    bf16x8 o;
#pragma unroll
    for (int j = 0; j < 8; ++j) o[j] = (bf16)acc[j];
    *reinterpret_cast<bf16x8*>(&att[(size_t)n * ldatt + lane * 8]) = o;
}

// ---------------- launch ----------------
extern "C" void kernel_launch(void* const* d_in, const int* in_sizes, int n_in,
                              void* d_out, int out_size, void* d_ws, size_t ws_size,
                              hipStream_t stream)
{
    const float* x   = (const float*)d_in[0];
    const float* pe  = (const float*)d_in[1];
    const int*   len = (const int*)d_in[2];
    const float* Wq  = (const float*)d_in[3];
    const float* bq  = (const float*)d_in[4];
    const float* Wk  = (const float*)d_in[5];
    const float* bk  = (const float*)d_in[6];
    const float* Wv  = (const float*)d_in[7];
    const float* bv  = (const float*)d_in[8];
    const float* Wo  = (const float*)d_in[9];
    const float* bo  = (const float*)d_in[10];
    float* out = (float*)d_out;

    const int n = in_sizes[0] / DEMB;    // 20000

    char* ws = (char*)d_ws;
    size_t off = 0;
    auto alloc = [&](size_t bytes) -> char* {
        char* p = ws + off;
        off += (bytes + 255) & ~(size_t)255;
        return p;
    };
    bf16*  WqT   = (bf16*)alloc((size_t)512 * 512 * 2);
    bf16*  WkvT  = (bf16*)alloc((size_t)1024 * 512 * 2); // rows 0-511 Wk^T, 512-1023 Wv^T
    bf16*  WoT   = (bf16*)alloc((size_t)512 * 1024 * 2);
    float* bkv   = (float*)alloc(1024 * 4);
    bf16*  Qb    = (bf16*)alloc((size_t)n * 512 * 2);
    bf16*  xa    = (bf16*)alloc((size_t)n * 1024 * 2);   // [x_bf16 || att]
    int*   startb= (int*)alloc((size_t)n * 4);
    int*   idxb  = (int*)alloc((size_t)n * PMAX * 4);
    int*   mlive = (int*)alloc(256);
    (void)n_in; (void)out_size;

    const size_t per_node = (size_t)PMAX * 1024 * 2;
    const size_t kv_avail = (ws_size > off) ? (ws_size - off) : 0;
    long long npc_ll = (long long)(kv_avail / per_node);
    int npc = (npc_ll >= n) ? n : (int)npc_ll;
    if (npc < 1) npc = 1;
    bf16* KVb = (bf16*)(ws + off);

    // prep
    transpose_to_bf16<<<dim3(16, 16), 256, 0, stream>>>(Wq, WqT, 512, 512);
    transpose_to_bf16<<<dim3(16, 16), 256, 0, stream>>>(Wk, WkvT, 512, 512);
    transpose_to_bf16<<<dim3(16, 16), 256, 0, stream>>>(Wv, WkvT + (size_t)512 * 512, 512, 512);
    transpose_to_bf16<<<dim3(16, 32), 256, 0, stream>>>(Wo, WoT, 1024, 512);
    concat_bias_kernel<<<4, 256, 0, stream>>>(bk, bv, bkv);
    x_to_xa<<<(n * 64 + 255) / 256, 256, 0, stream>>>(x, xa, n * 64);

    // Q = x @ Wq + bq -> Qb bf16 [n][512]   (N=512 -> NT=4, LNT=2)
    {
        const int MT = (n + 127) / 128, MTp = ((MT + 7) / 8) * 8;
        gemm97<0, 2><<<MTp * 4, 256, 0, stream>>>(
            xa, 1024, WqT, bq, n, nullptr, nullptr, 512, nullptr, Qb, 512);
    }

    if (npc >= n) {
        // ---- compacted single-pass path ----
        scan_lens<<<1, 1024, 0, stream>>>(len, n, startb, mlive);
        build_idx<<<(n + 255) / 256, 256, 0, stream>>>(len, startb, idxb, n);
        // KV = pe[live rows] @ [Wk|Wv] + bkv -> KVb [M_live][1024]  (NT=8, LNT=3)
        {
            const int MT = (n * PMAX + 127) / 128, MTp = ((MT + 7) / 8) * 8;
            gemm97<2, 3><<<MTp * 8, 256, 0, stream>>>(
                pe, 512, WkvT, bkv, n * PMAX, mlive, idxb, 512, nullptr, KVb, 1024);
        }
        attn_kernel<<<(n + 3) / 4, 256, 0, stream>>>(
            Qb, KVb, len, startb, xa + 512, 1024, n);
    } else {
        // ---- fallback: chunked, uncompacted ----
        for (int node0 = 0; node0 < n; node0 += npc) {
            const int nn = (n - node0 < npc) ? (n - node0) : npc;
            const int M  = nn * PMAX;
            const int MT = (M + 127) / 128, MTp = ((MT + 7) / 8) * 8;
            gemm97<1, 3><<<MTp * 8, 256, 0, stream>>>(
                pe + (size_t)node0 * PMAX * 512, 512, WkvT, bkv, M, nullptr, nullptr,
                512, nullptr, KVb, 1024);
            attn_kernel<<<(nn + 3) / 4, 256, 0, stream>>>(
                Qb + (size_t)node0 * 512, KVb, len + node0, nullptr,
                xa + (size_t)node0 * 1024 + 512, 1024, nn);
        }
    }

    // out = [x || att] @ Wo + bo -> f32 [n][512]   (NT=4, LNT=2)
    {
        const int MT = (n + 127) / 128, MTp = ((MT + 7) / 8) * 8;
        gemm97<0, 2><<<MTp * 4, 256, 0, stream>>>(
            xa, 1024, WoT, bo, n, nullptr, nullptr, 1024, out, nullptr, 512);
    }
}